// Round 5
// baseline (1571.053 us; speedup 1.0000x reference)
//
#include <hip/hip_runtime.h>
#include <math.h>

#define N_CELL 400000
#define N_NET  100000
#define E_PIN  1600000
#define E2     400000

// ================= CSR build =================

__global__ void __launch_bounds__(256) k_hist(
    const int* __restrict__ src, const int* __restrict__ dst,
    int* __restrict__ cell_deg, int* __restrict__ net_deg)
{
    int e = blockIdx.x * 256 + threadIdx.x;
    if (e >= E_PIN) return;
    atomicAdd(&net_deg[dst[e]], 1);
    atomicAdd(&cell_deg[src[e]], 1);
}

__global__ void __launch_bounds__(256) k_alloc(
    const int* __restrict__ deg, int* __restrict__ ptr, int* __restrict__ cur,
    int* __restrict__ cursor, int n)
{
    __shared__ int s[256];
    __shared__ int base;
    int tid = threadIdx.x;
    int i = blockIdx.x * 256 + tid;
    int d = (i < n) ? deg[i] : 0;
    int v = d;
    s[tid] = v;
    __syncthreads();
    for (int o = 1; o < 256; o <<= 1) {
        int t = (tid >= o) ? s[tid - o] : 0;
        __syncthreads();
        v += t;
        s[tid] = v;
        __syncthreads();
    }
    if (tid == 255) base = atomicAdd(cursor, v);
    __syncthreads();
    if (i < n) {
        int p = base + v - d;
        ptr[i] = p;
        cur[i] = p;
    }
}

__global__ void __launch_bounds__(256) k_fill(
    const int* __restrict__ src, const int* __restrict__ dst,
    int* __restrict__ net_cur, int* __restrict__ cell_cur,
    int* __restrict__ csr_net_cell, int* __restrict__ csr_cell_net,
    int* __restrict__ edge_slot)
{
    int e = blockIdx.x * 256 + threadIdx.x;
    if (e >= E_PIN) return;
    int s = src[e], d = dst[e];
    int p = atomicAdd(&net_cur[d], 1);
    csr_net_cell[p] = s;
    int q = atomicAdd(&cell_cur[s], 1);
    csr_cell_net[q] = d;
    edge_slot[e] = q;
}

// ======== fused gather (mean+max) + 24x64 node MLP, tiled GEMM ========
// 512 thr = 8 waves; tile = 64 rows. Gather: wave w rows w*8..w*8+7.
// Matmul: lane (r=l>>3, cg=l&7) computes row w*8+r, cols cg*8..cg*8+7.
__global__ void __launch_bounds__(512) k_node(
    const float* __restrict__ self_feat, const float* __restrict__ other_feat,
    const int* __restrict__ ptr, const int* __restrict__ deg_a,
    const int* __restrict__ csr,
    const float* __restrict__ W, const float* __restrict__ b,
    float* __restrict__ out, int nrows)
{
    __shared__ float Ws[24 * 64];      // [k][c]
    __shared__ float bs[64];
    __shared__ float X[64][25];        // padded: banks (25r+k)%32 distinct over r
    int tid = threadIdx.x;
    for (int i = tid; i < 24 * 64; i += 512) Ws[i] = W[i];
    if (tid < 64) bs[tid] = b[tid];
    int w = tid >> 6, l = tid & 63;
    int tile = blockIdx.x * 64;
    int g = l >> 3, k = l & 7;
    for (int r8 = 0; r8 < 8; ++r8) {
        int lrow = w * 8 + r8;
        int row = tile + lrow;
        if (row >= nrows) break;
        int base = ptr[row], deg = deg_a[row];
        float sum = 0.0f, mx = -INFINITY;
        for (int j0 = 0; j0 < deg; j0 += 64) {
            int j = j0 + l;
            int idx_j = (j < deg) ? csr[base + j] : 0;     // coalesced
            int lim = deg - j0; if (lim > 64) lim = 64;
            for (int t = 0; t < lim; t += 8) {
                int te = t + g;
                int idx = __shfl(idx_j, te);
                if (te < lim) {
                    float v = other_feat[idx * 8 + k];
                    sum += v;
                    mx = fmaxf(mx, v);
                }
            }
        }
        #pragma unroll
        for (int o = 8; o < 64; o <<= 1) {
            sum += __shfl_xor(sum, o);
            mx = fmaxf(mx, __shfl_xor(mx, o));
        }
        if (l < 8) {
            X[lrow][k] = self_feat[row * 8 + k];
            X[lrow][8 + k] = sum * (deg > 0 ? 1.0f / (float)deg : 1.0f);
            X[lrow][16 + k] = (deg > 0) ? mx : 0.0f;
        }
    }
    __syncthreads();
    int r = l >> 3, cg = l & 7;
    int row = tile + w * 8 + r;
    float acc[8];
    #pragma unroll
    for (int c = 0; c < 8; ++c) acc[c] = bs[cg * 8 + c];
    for (int kk = 0; kk < 24; ++kk) {
        float x = X[w * 8 + r][kk];
        #pragma unroll
        for (int c = 0; c < 8; ++c) acc[c] += x * Ws[kk * 64 + cg * 8 + c];
    }
    if (row < nrows) {
        float4 o0 = make_float4(tanhf(acc[0]), tanhf(acc[1]), tanhf(acc[2]), tanhf(acc[3]));
        float4 o1 = make_float4(tanhf(acc[4]), tanhf(acc[5]), tanhf(acc[6]), tanhf(acc[7]));
        *(float4*)&out[row * 64 + cg * 8] = o0;
        *(float4*)&out[row * 64 + cg * 8 + 4] = o1;
    }
}

// ==== per-pin edge weight, scattered into CSR slot order ====
__global__ void __launch_bounds__(256) k_ew(
    const float* __restrict__ pin_feat,
    const float* __restrict__ W_pin, const float* __restrict__ b_pin,
    const float* __restrict__ W_ew, const float* __restrict__ b_ew,
    const int* __restrict__ edge_slot,
    float* __restrict__ ew_csr)
{
    __shared__ float Wp[8 * 16];
    __shared__ float bp[16];
    __shared__ float We[16];
    __shared__ float be_s;
    int tid = threadIdx.x;
    if (tid < 128) Wp[tid] = W_pin[tid];
    if (tid < 16) { bp[tid] = b_pin[tid]; We[tid] = W_ew[tid]; }
    if (tid == 0) be_s = b_ew[0];
    __syncthreads();
    int e = blockIdx.x * 256 + tid;
    if (e >= E_PIN) return;
    float p[8];
    #pragma unroll
    for (int k = 0; k < 8; ++k) p[k] = pin_feat[e * 8 + k];
    float acc = be_s;
    #pragma unroll
    for (int j = 0; j < 16; ++j) {
        float h = bp[j];
        #pragma unroll
        for (int k = 0; k < 8; ++k) h += p[k] * Wp[k * 16 + j];
        acc += tanhf(h) * We[j];
    }
    ew_csr[edge_slot[e]] = tanhf(acc);
}

// ==== fused SAGE hidden, tiled GEMM (exactly 64KB LDS) ====
// hc := hc@Wself + (mean of ew*hn)@Wneigh + b, in place, 64-row tiles.
// X/XN use XOR col-swizzle (col' = col ^ (row&7)) for conflict-free reads.
__global__ void __launch_bounds__(512) k_hidden(
    float* __restrict__ hc, const float* __restrict__ hn,
    const float* __restrict__ ew_csr,
    const int* __restrict__ ptr, const int* __restrict__ deg_a,
    const int* __restrict__ csr_net,
    const float* __restrict__ Wself, const float* __restrict__ Wneigh,
    const float* __restrict__ bsage)
{
    __shared__ float Ws[64 * 64];      // 16KB
    __shared__ float Wn[64 * 64];      // 16KB
    __shared__ float X[64][64];        // 16KB, swizzled
    __shared__ float XN[64][64];       // 16KB, swizzled
    int tid = threadIdx.x;
    for (int i = tid; i < 64 * 64; i += 512) { Ws[i] = Wself[i]; Wn[i] = Wneigh[i]; }
    int w = tid >> 6, l = tid & 63;
    int tile = blockIdx.x * 64;        // N_CELL/64 = 6250 exact
    for (int r8 = 0; r8 < 8; ++r8) {
        int lrow = w * 8 + r8;
        int row = tile + lrow;
        int base = ptr[row], deg = deg_a[row];
        float accn = 0.0f;
        for (int j0 = 0; j0 < deg; j0 += 64) {
            int j = j0 + l;
            int net_j = 0; float ew_j = 0.0f;
            if (j < deg) {
                net_j = csr_net[base + j];     // coalesced
                ew_j  = ew_csr[base + j];      // coalesced (pre-permuted)
            }
            int lim = deg - j0; if (lim > 64) lim = 64;
            for (int t = 0; t < lim; ++t) {
                int net = __shfl(net_j, t);
                float wt = __shfl(ew_j, t);
                accn += wt * hn[net * 64 + l]; // independent 256B row loads
            }
        }
        int sc = l ^ (lrow & 7);               // XOR swizzle
        X[lrow][sc]  = hc[row * 64 + l];
        XN[lrow][sc] = accn * (deg > 0 ? 1.0f / (float)deg : 0.0f);
    }
    __syncthreads();
    int r = l >> 3, cg = l & 7;
    int row = tile + w * 8 + r;
    float4 b0 = *(const float4*)&bsage[cg * 8];
    float4 b1 = *(const float4*)&bsage[cg * 8 + 4];
    float acc[8] = {b0.x, b0.y, b0.z, b0.w, b1.x, b1.y, b1.z, b1.w};
    int lrow = w * 8 + r;
    for (int kk = 0; kk < 64; ++kk) {
        float xc = X[lrow][kk ^ r];            // banks distinct over r
        float xn = XN[lrow][kk ^ r];
        #pragma unroll
        for (int c = 0; c < 8; ++c)
            acc[c] += xc * Ws[kk * 64 + cg * 8 + c] + xn * Wn[kk * 64 + cg * 8 + c];
    }
    float4 o0 = make_float4(acc[0], acc[1], acc[2], acc[3]);
    float4 o1 = make_float4(acc[4], acc[5], acc[6], acc[7]);
    *(float4*)&hc[row * 64 + cg * 8] = o0;     // safe: tile staged before barrier
    *(float4*)&hc[row * 64 + cg * 8 + 4] = o1;
}

// ============ edge readout: one 64-lane wave per edge ============
__global__ void __launch_bounds__(256) k_edge(
    const float* __restrict__ hidden, const float* __restrict__ hn,
    const int* __restrict__ fa, const int* __restrict__ so, const int* __restrict__ gf,
    const int* __restrict__ fsn, const int* __restrict__ gfn,
    const float* __restrict__ W_dis, const float* __restrict__ b_dis,
    const float* __restrict__ W_def, const float* __restrict__ b_def,
    const float* __restrict__ cell_size, float* __restrict__ out)
{
    int e = blockIdx.x * 4 + (threadIdx.x >> 6);
    int l = threadIdx.x & 63;
    if (e >= E2) return;
    int f = fa[e], s = so[e], g = gf[e], nf = fsn[e], ng = gfn[e];
    float hf = hidden[f * 64 + l];
    float hs = hidden[s * 64 + l];
    float hg = hidden[g * 64 + l];
    float vnf = hn[nf * 64 + l];
    float vng = hn[ng * 64 + l];
    float dis = hf * W_dis[l] + hs * W_dis[64 + l] + vnf * W_dis[128 + l];
    float de  = hg * W_def[l] + hf * W_def[64 + l] + hs * W_def[128 + l]
              + vng * W_def[192 + l] + vnf * W_def[256 + l];
    #pragma unroll
    for (int o = 32; o > 0; o >>= 1) {
        dis += __shfl_down(dis, o);
        de  += __shfl_down(de, o);
    }
    if (l == 0) {
        float d1 = expf(-2.0f + 15.0f * tanhf(dis + b_dis[0]));
        float d2 = tanhf(de + b_def[0]) * 6.28318530717958647692f;
        float bx = (cell_size[f * 2 + 0] + cell_size[s * 2 + 0]) * 0.5f;
        float by = (cell_size[f * 2 + 1] + cell_size[s * 2 + 1]) * 0.5f;
        out[e] = d1 + fminf(bx, by);
        out[E2 + e] = d2;
    }
}

extern "C" void kernel_launch(void* const* d_in, const int* in_sizes, int n_in,
                              void* d_out, int out_size, void* d_ws, size_t ws_size,
                              hipStream_t stream)
{
    const float* cell_feat = (const float*)d_in[0];
    const float* net_feat  = (const float*)d_in[1];
    const float* pin_feat  = (const float*)d_in[2];
    const float* cell_size = (const float*)d_in[3];
    const float* W_cell = (const float*)d_in[4];
    const float* b_cell = (const float*)d_in[5];
    const float* W_net  = (const float*)d_in[6];
    const float* b_net  = (const float*)d_in[7];
    const float* W_pin  = (const float*)d_in[8];
    const float* b_pin  = (const float*)d_in[9];
    const float* W_ew   = (const float*)d_in[10];
    const float* b_ew   = (const float*)d_in[11];
    const float* W_self = (const float*)d_in[12];
    const float* W_neigh= (const float*)d_in[13];
    const float* b_sage = (const float*)d_in[14];
    const float* W_dis  = (const float*)d_in[15];
    const float* b_dis  = (const float*)d_in[16];
    const float* W_def  = (const float*)d_in[17];
    const float* b_def  = (const float*)d_in[18];
    const int* pins_src = (const int*)d_in[19];
    const int* pins_dst = (const int*)d_in[20];
    const int* fathers  = (const int*)d_in[21];
    const int* sons     = (const int*)d_in[22];
    const int* grandf   = (const int*)d_in[23];
    const int* fs_nets  = (const int*)d_in[24];
    const int* gf_nets  = (const int*)d_in[25];

    // ---- workspace layout (256B aligned) ----
    char* ws = (char*)d_ws;
    size_t off = 0;
    auto alloc = [&](size_t bytes) -> void* {
        void* p = ws + off;
        off += (bytes + 255) & ~(size_t)255;
        return p;
    };
    int* cursors   = (int*)alloc(2 * 4);
    int* net_deg   = (int*)alloc((size_t)N_NET * 4);
    int* cell_deg  = (int*)alloc((size_t)N_CELL * 4);
    size_t zero_bytes = off;
    int* net_ptr   = (int*)alloc((size_t)N_NET * 4);
    int* net_cur   = (int*)alloc((size_t)N_NET * 4);
    int* cell_ptr  = (int*)alloc((size_t)N_CELL * 4);
    int* cell_cur  = (int*)alloc((size_t)N_CELL * 4);
    int* csr_net_cell = (int*)alloc((size_t)E_PIN * 4);   // cell idx per net-slot
    int* csr_cell_net = (int*)alloc((size_t)E_PIN * 4);   // net idx per cell-slot
    int* edge_slot    = (int*)alloc((size_t)E_PIN * 4);   // cell-slot of edge e
    float* ew_csr  = (float*)alloc((size_t)E_PIN * 4);    // ew in cell-slot order
    float* hc = (float*)alloc((size_t)N_CELL * 64 * 4);   // becomes hidden in place
    float* hn = (float*)alloc((size_t)N_NET * 64 * 4);
    if (off > ws_size) return;   // fail loudly (absmax), don't fault

    hipMemsetAsync(d_ws, 0, zero_bytes, stream);

    // CSR build
    k_hist<<<(E_PIN + 255) / 256, 256, 0, stream>>>(pins_src, pins_dst, cell_deg, net_deg);
    k_alloc<<<(N_NET + 255) / 256, 256, 0, stream>>>(net_deg, net_ptr, net_cur, &cursors[0], N_NET);
    k_alloc<<<(N_CELL + 255) / 256, 256, 0, stream>>>(cell_deg, cell_ptr, cell_cur, &cursors[1], N_CELL);
    k_fill<<<(E_PIN + 255) / 256, 256, 0, stream>>>(
        pins_src, pins_dst, net_cur, cell_cur, csr_net_cell, csr_cell_net, edge_slot);

    // fused gather + node MLPs (tiled)
    k_node<<<(N_NET + 63) / 64, 512, 0, stream>>>(
        net_feat, cell_feat, net_ptr, net_deg, csr_net_cell, W_net, b_net, hn, N_NET);
    k_node<<<(N_CELL + 63) / 64, 512, 0, stream>>>(
        cell_feat, net_feat, cell_ptr, cell_deg, csr_cell_net, W_cell, b_cell, hc, N_CELL);

    // edge weights, scattered to CSR slot order
    k_ew<<<(E_PIN + 255) / 256, 256, 0, stream>>>(
        pin_feat, W_pin, b_pin, W_ew, b_ew, edge_slot, ew_csr);

    // fused SAGE hidden (tiled GEMM), in place over hc
    k_hidden<<<N_CELL / 64, 512, 0, stream>>>(
        hc, hn, ew_csr, cell_ptr, cell_deg, csr_cell_net, W_self, W_neigh, b_sage);

    // edge readouts
    k_edge<<<E2 / 4, 256, 0, stream>>>(
        hc, hn, fathers, sons, grandf, fs_nets, gf_nets,
        W_dis, b_dis, W_def, b_def, cell_size, (float*)d_out);
}

// Round 6
// 1056.000 us; speedup vs baseline: 1.4877x; 1.4877x over previous
//
#include <hip/hip_runtime.h>
#include <math.h>

#define N_CELL 400000
#define N_NET  100000
#define E_PIN  1600000
#define E2     400000

// ================= CSR build =================

__global__ void __launch_bounds__(256) k_hist(
    const int* __restrict__ src, const int* __restrict__ dst,
    int* __restrict__ cell_deg, int* __restrict__ net_deg)
{
    int e = blockIdx.x * 256 + threadIdx.x;
    if (e >= E_PIN) return;
    atomicAdd(&net_deg[dst[e]], 1);
    atomicAdd(&cell_deg[src[e]], 1);
}

__global__ void __launch_bounds__(256) k_alloc(
    const int* __restrict__ deg, int* __restrict__ ptr, int* __restrict__ cur,
    int* __restrict__ cursor, int n)
{
    __shared__ int s[256];
    __shared__ int base;
    int tid = threadIdx.x;
    int i = blockIdx.x * 256 + tid;
    int d = (i < n) ? deg[i] : 0;
    int v = d;
    s[tid] = v;
    __syncthreads();
    for (int o = 1; o < 256; o <<= 1) {
        int t = (tid >= o) ? s[tid - o] : 0;
        __syncthreads();
        v += t;
        s[tid] = v;
        __syncthreads();
    }
    if (tid == 255) base = atomicAdd(cursor, v);
    __syncthreads();
    if (i < n) {
        int p = base + v - d;
        ptr[i] = p;
        cur[i] = p;
    }
}

__global__ void __launch_bounds__(256) k_fill(
    const int* __restrict__ src, const int* __restrict__ dst,
    int* __restrict__ net_cur, int* __restrict__ cell_cur,
    int* __restrict__ csr_net_cell, int* __restrict__ csr_cell_net,
    int* __restrict__ edge_slot)
{
    int e = blockIdx.x * 256 + threadIdx.x;
    if (e >= E_PIN) return;
    int s = src[e], d = dst[e];
    int p = atomicAdd(&net_cur[d], 1);
    csr_net_cell[p] = s;
    int q = atomicAdd(&cell_cur[s], 1);
    csr_cell_net[q] = d;
    edge_slot[e] = q;
}

// ==== per-pin edge weight, scattered into cell-CSR slot order ====
__global__ void __launch_bounds__(256) k_ew(
    const float* __restrict__ pin_feat,
    const float* __restrict__ W_pin, const float* __restrict__ b_pin,
    const float* __restrict__ W_ew, const float* __restrict__ b_ew,
    const int* __restrict__ edge_slot,
    float* __restrict__ ew_csr)
{
    __shared__ float Wp[8 * 16];
    __shared__ float bp[16];
    __shared__ float We[16];
    __shared__ float be_s;
    int tid = threadIdx.x;
    if (tid < 128) Wp[tid] = W_pin[tid];
    if (tid < 16) { bp[tid] = b_pin[tid]; We[tid] = W_ew[tid]; }
    if (tid == 0) be_s = b_ew[0];
    __syncthreads();
    int e = blockIdx.x * 256 + tid;
    if (e >= E_PIN) return;
    float p[8];
    #pragma unroll
    for (int k = 0; k < 8; ++k) p[k] = pin_feat[e * 8 + k];
    float acc = be_s;
    #pragma unroll
    for (int j = 0; j < 16; ++j) {
        float h = bp[j];
        #pragma unroll
        for (int k = 0; k < 8; ++k) h += p[k] * Wp[k * 16 + j];
        acc += tanhf(h) * We[j];
    }
    ew_csr[edge_slot[e]] = tanhf(acc);
}

// ==== fused NET kernel: gather + 24x64 MLP -> hn (LDS only) ->
//      hnW = hn@W_neigh (global) + 3-scalar net pack ====
// 256 thr (4 waves), 64-row tile. LDS 46.6KB.
__global__ void __launch_bounds__(256) k_net(
    const float* __restrict__ net_feat, const float* __restrict__ cell_feat,
    const int* __restrict__ net_ptr, const int* __restrict__ net_deg,
    const int* __restrict__ csr_cell,
    const float* __restrict__ W_net, const float* __restrict__ b_net,
    const float* __restrict__ W_neigh,
    const float* __restrict__ W_dis, const float* __restrict__ W_def,
    float* __restrict__ hnW, float* __restrict__ npack)
{
    __shared__ float smem[11648];
    float* xs24 = smem;                 // [64][25]   1600
    float* Ws24 = smem + 1600;          // [24][64]   1536
    float* HN   = smem + 3136;          // [64][65]   4160
    float* Wn   = smem + 7296;          // [64][64]   4096
    float* Wd3  = smem + 11392;         // [3][64]     192
    float* bs   = smem + 11584;         // [64]         64

    int tid = threadIdx.x;
    int w = tid >> 6, l = tid & 63;
    int tile = blockIdx.x * 64;

    for (int i = tid; i < 1536; i += 256) Ws24[i] = W_net[i];
    for (int i = tid; i < 4096; i += 256) Wn[i] = W_neigh[i];
    if (tid < 192) Wd3[tid] = (tid < 64) ? W_dis[128 + tid] : W_def[128 + tid];
    if (tid < 64) bs[tid] = b_net[tid];

    // P1: gather cell_feat mean/max (group-of-8 per row)
    int g = l >> 3, k = l & 7;
    #pragma unroll
    for (int p = 0; p < 2; ++p) {
        int rl = p * 32 + w * 8 + g;
        int row = tile + rl;
        int base = 0, deg = 0;
        if (row < N_NET) { base = net_ptr[row]; deg = net_deg[row]; }
        float sum = 0.0f, mx = -INFINITY;
        for (int j = 0; j < deg; ++j) {
            int idx = csr_cell[base + j];
            float v = cell_feat[idx * 8 + k];
            sum += v;
            mx = fmaxf(mx, v);
        }
        float inv = (deg > 0) ? 1.0f / (float)deg : 1.0f;
        float sf = (row < N_NET) ? net_feat[row * 8 + k] : 0.0f;
        xs24[rl * 25 + k] = sf;
        xs24[rl * 25 + 8 + k] = sum * inv;
        xs24[rl * 25 + 16 + k] = (deg > 0) ? mx : 0.0f;
    }
    __syncthreads();

    // P2: hn = tanh(xs24 @ W_net + b) -> HN tile
    int rg = l >> 2, cc = l & 3, c0 = w * 16 + cc * 4;
    {
        float acc[4][4];
        #pragma unroll
        for (int i = 0; i < 4; ++i) {
            float4 b4 = *(const float4*)&bs[c0];
            acc[i][0] = b4.x; acc[i][1] = b4.y; acc[i][2] = b4.z; acc[i][3] = b4.w;
        }
        for (int kk = 0; kk < 24; ++kk) {
            float4 wv = *(const float4*)&Ws24[kk * 64 + c0];
            #pragma unroll
            for (int i = 0; i < 4; ++i) {
                float x = xs24[(rg * 4 + i) * 25 + kk];
                acc[i][0] += x * wv.x; acc[i][1] += x * wv.y;
                acc[i][2] += x * wv.z; acc[i][3] += x * wv.w;
            }
        }
        #pragma unroll
        for (int i = 0; i < 4; ++i)
            #pragma unroll
            for (int j = 0; j < 4; ++j)
                HN[(rg * 4 + i) * 65 + c0 + j] = tanhf(acc[i][j]);
    }
    __syncthreads();

    // P3: hnW = HN @ W_neigh -> global
    {
        float acc[4][4];
        #pragma unroll
        for (int i = 0; i < 4; ++i)
            #pragma unroll
            for (int j = 0; j < 4; ++j) acc[i][j] = 0.0f;
        for (int kk = 0; kk < 64; ++kk) {
            float4 wv = *(const float4*)&Wn[kk * 64 + c0];
            #pragma unroll
            for (int i = 0; i < 4; ++i) {
                float x = HN[(rg * 4 + i) * 65 + kk];
                acc[i][0] += x * wv.x; acc[i][1] += x * wv.y;
                acc[i][2] += x * wv.z; acc[i][3] += x * wv.w;
            }
        }
        #pragma unroll
        for (int i = 0; i < 4; ++i) {
            int row = tile + rg * 4 + i;
            if (row < N_NET)
                *(float4*)&hnW[(size_t)row * 64 + c0] =
                    make_float4(acc[i][0], acc[i][1], acc[i][2], acc[i][3]);
        }
    }

    // P4: net pack: npack[row][d] = hn . Wd3[d], d<3 (d==3 -> 0)
    {
        int row = tid & 63, d = tid >> 6;
        float a = 0.0f;
        if (d < 3)
            for (int kk = 0; kk < 64; ++kk) a += HN[row * 65 + kk] * Wd3[d * 64 + kk];
        int grow = tile + row;
        if (grow < N_NET) npack[(size_t)grow * 4 + d] = (d < 3) ? a : 0.0f;
    }
}

// ==== fused CELL kernel: gather(net mean/max + ew*hnW) + 24x64 MLP ->
//      hc (LDS) -> hidden = hc@Wself + xn + b -> 5-scalar pack + sizes ====
// 256 thr (4 waves), 64-row tile (N_CELL/64 exact). LDS 51.5KB.
__global__ void __launch_bounds__(256) k_cell(
    const float* __restrict__ cell_feat, const float* __restrict__ net_feat,
    const float* __restrict__ cell_size,
    const int* __restrict__ cell_ptr, const int* __restrict__ cell_deg,
    const int* __restrict__ csr_net, const float* __restrict__ ew_csr,
    const float* __restrict__ hnW,
    const float* __restrict__ W_cell, const float* __restrict__ b_cell,
    const float* __restrict__ W_self, const float* __restrict__ b_sage,
    const float* __restrict__ W_dis, const float* __restrict__ W_def,
    float* __restrict__ cellpack)
{
    __shared__ float smem[12864];
    // region0: xs24[64][25] (1600) + Ws24[24][64] (1536) = 3136, overlaid later by XN[64][65] (4160)
    float* xs24 = smem;
    float* Ws24 = smem + 1600;
    float* XN   = smem;                 // overlay after P2
    float* X    = smem + 4160;          // [64][65] 4160 (hc then hidden)
    float* Wsf  = smem + 8320;          // [64][64] 4096
    float* Wd5  = smem + 12416;         // [5][64]   320
    float* bs24 = smem + 12736;         // [64]
    float* bsg  = smem + 12800;         // [64]

    int tid = threadIdx.x;
    int w = tid >> 6, l = tid & 63;
    int tile = blockIdx.x * 64;

    for (int i = tid; i < 1536; i += 256) Ws24[i] = W_cell[i];
    for (int i = tid; i < 4096; i += 256) Wsf[i] = W_self[i];
    if (tid < 64) { bs24[tid] = b_cell[tid]; bsg[tid] = b_sage[tid]; }
    { int i = tid; if (i < 320) Wd5[i] = (i < 128) ? W_dis[i] : W_def[i - 128]; }

    // P1: merged gather: net_feat mean/max (dim k) + ew*hnW (dims k*8..k*8+7)
    int g = l >> 3, k = l & 7;
    float4 xa[2], xb[2];
    #pragma unroll
    for (int p = 0; p < 2; ++p) {
        int rl = p * 32 + w * 8 + g;
        int row = tile + rl;
        int base = cell_ptr[row], deg = cell_deg[row];
        float sum = 0.0f, mx = -INFINITY;
        float4 a0 = make_float4(0, 0, 0, 0), a1 = make_float4(0, 0, 0, 0);
        for (int j = 0; j < deg; ++j) {
            int slot = base + j;
            int net = csr_net[slot];
            float wt = ew_csr[slot];
            float v = net_feat[net * 8 + k];
            sum += v;
            mx = fmaxf(mx, v);
            const float4* hp = (const float4*)(hnW + (size_t)net * 64 + k * 8);
            float4 u = hp[0], u2 = hp[1];
            a0.x += wt * u.x;  a0.y += wt * u.y;  a0.z += wt * u.z;  a0.w += wt * u.w;
            a1.x += wt * u2.x; a1.y += wt * u2.y; a1.z += wt * u2.z; a1.w += wt * u2.w;
        }
        float inv = (deg > 0) ? 1.0f / (float)deg : 1.0f;
        xs24[rl * 25 + k] = cell_feat[row * 8 + k];
        xs24[rl * 25 + 8 + k] = sum * inv;
        xs24[rl * 25 + 16 + k] = (deg > 0) ? mx : 0.0f;
        xa[p] = make_float4(a0.x * inv, a0.y * inv, a0.z * inv, a0.w * inv);
        xb[p] = make_float4(a1.x * inv, a1.y * inv, a1.z * inv, a1.w * inv);
    }
    __syncthreads();

    // P2: hc = tanh(xs24 @ W_cell + b) -> X tile
    int rg = l >> 2, cc = l & 3, c0 = w * 16 + cc * 4;
    {
        float acc[4][4];
        #pragma unroll
        for (int i = 0; i < 4; ++i) {
            float4 b4 = *(const float4*)&bs24[c0];
            acc[i][0] = b4.x; acc[i][1] = b4.y; acc[i][2] = b4.z; acc[i][3] = b4.w;
        }
        for (int kk = 0; kk < 24; ++kk) {
            float4 wv = *(const float4*)&Ws24[kk * 64 + c0];
            #pragma unroll
            for (int i = 0; i < 4; ++i) {
                float x = xs24[(rg * 4 + i) * 25 + kk];
                acc[i][0] += x * wv.x; acc[i][1] += x * wv.y;
                acc[i][2] += x * wv.z; acc[i][3] += x * wv.w;
            }
        }
        __syncthreads();   // xs24 fully consumed; region0 becomes XN
        #pragma unroll
        for (int i = 0; i < 4; ++i)
            #pragma unroll
            for (int j = 0; j < 4; ++j)
                X[(rg * 4 + i) * 65 + c0 + j] = tanhf(acc[i][j]);
    }
    // P2b: write XN (neighbor term) from registers
    #pragma unroll
    for (int p = 0; p < 2; ++p) {
        int rl = p * 32 + w * 8 + g;
        float* xn = &XN[rl * 65 + k * 8];
        xn[0] = xa[p].x; xn[1] = xa[p].y; xn[2] = xa[p].z; xn[3] = xa[p].w;
        xn[4] = xb[p].x; xn[5] = xb[p].y; xn[6] = xb[p].z; xn[7] = xb[p].w;
    }
    __syncthreads();

    // P5: hidden = X @ W_self + XN + b_sage  (then write back into X)
    {
        float acc[4][4];
        #pragma unroll
        for (int i = 0; i < 4; ++i) {
            float4 b4 = *(const float4*)&bsg[c0];
            int r = rg * 4 + i;
            acc[i][0] = b4.x + XN[r * 65 + c0];
            acc[i][1] = b4.y + XN[r * 65 + c0 + 1];
            acc[i][2] = b4.z + XN[r * 65 + c0 + 2];
            acc[i][3] = b4.w + XN[r * 65 + c0 + 3];
        }
        for (int kk = 0; kk < 64; ++kk) {
            float4 wv = *(const float4*)&Wsf[kk * 64 + c0];
            #pragma unroll
            for (int i = 0; i < 4; ++i) {
                float x = X[(rg * 4 + i) * 65 + kk];
                acc[i][0] += x * wv.x; acc[i][1] += x * wv.y;
                acc[i][2] += x * wv.z; acc[i][3] += x * wv.w;
            }
        }
        __syncthreads();   // everyone done reading X (hc)
        #pragma unroll
        for (int i = 0; i < 4; ++i)
            #pragma unroll
            for (int j = 0; j < 4; ++j)
                X[(rg * 4 + i) * 65 + c0 + j] = acc[i][j];
    }
    __syncthreads();

    // P6: cell pack: [d0..d4, sx, sy, 0]
    {
        int row = tid & 63, d = tid >> 6;
        float a = 0.0f, a2 = 0.0f;
        for (int kk = 0; kk < 64; ++kk) {
            float x = X[row * 65 + kk];
            a += x * Wd5[d * 64 + kk];
            if (d == 0) a2 += x * Wd5[256 + kk];
        }
        size_t gbase = (size_t)(tile + row) * 8;
        cellpack[gbase + d] = a;
        if (d == 0) cellpack[gbase + 4] = a2;
        else if (d == 1) cellpack[gbase + 5] = cell_size[(size_t)(tile + row) * 2];
        else if (d == 2) cellpack[gbase + 6] = cell_size[(size_t)(tile + row) * 2 + 1];
        else cellpack[gbase + 7] = 0.0f;
    }
}

// ============ edge readout: one thread per edge, scalar packs ============
__global__ void __launch_bounds__(256) k_edge(
    const float* __restrict__ cellpack, const float* __restrict__ npack,
    const int* __restrict__ fa, const int* __restrict__ so, const int* __restrict__ gf,
    const int* __restrict__ fsn, const int* __restrict__ gfn,
    const float* __restrict__ b_dis, const float* __restrict__ b_def,
    float* __restrict__ out)
{
    int e = blockIdx.x * 256 + threadIdx.x;
    if (e >= E2) return;
    int f = fa[e], s = so[e], g = gf[e], nf = fsn[e], ng = gfn[e];
    const float4* cf = (const float4*)(cellpack + (size_t)f * 8);
    float4 f0 = cf[0], f1 = cf[1];
    const float4* cs = (const float4*)(cellpack + (size_t)s * 8);
    float4 s0 = cs[0], s1 = cs[1];
    float g2 = cellpack[(size_t)g * 8 + 2];
    float4 n0 = *(const float4*)(npack + (size_t)nf * 4);
    float ng1 = npack[(size_t)ng * 4 + 1];
    float dis = f0.x + s0.y + n0.x + b_dis[0];
    float defl = g2 + f0.w + s1.x + ng1 + n0.z + b_def[0];
    float o1 = expf(-2.0f + 15.0f * tanhf(dis));
    float bx = (f1.y + s1.y) * 0.5f;
    float by = (f1.z + s1.z) * 0.5f;
    out[e] = o1 + fminf(bx, by);
    out[E2 + e] = tanhf(defl) * 6.28318530717958647692f;
}

extern "C" void kernel_launch(void* const* d_in, const int* in_sizes, int n_in,
                              void* d_out, int out_size, void* d_ws, size_t ws_size,
                              hipStream_t stream)
{
    const float* cell_feat = (const float*)d_in[0];
    const float* net_feat  = (const float*)d_in[1];
    const float* pin_feat  = (const float*)d_in[2];
    const float* cell_size = (const float*)d_in[3];
    const float* W_cell = (const float*)d_in[4];
    const float* b_cell = (const float*)d_in[5];
    const float* W_net  = (const float*)d_in[6];
    const float* b_net  = (const float*)d_in[7];
    const float* W_pin  = (const float*)d_in[8];
    const float* b_pin  = (const float*)d_in[9];
    const float* W_ew   = (const float*)d_in[10];
    const float* b_ew   = (const float*)d_in[11];
    const float* W_self = (const float*)d_in[12];
    const float* W_neigh= (const float*)d_in[13];
    const float* b_sage = (const float*)d_in[14];
    const float* W_dis  = (const float*)d_in[15];
    const float* b_dis  = (const float*)d_in[16];
    const float* W_def  = (const float*)d_in[17];
    const float* b_def  = (const float*)d_in[18];
    const int* pins_src = (const int*)d_in[19];
    const int* pins_dst = (const int*)d_in[20];
    const int* fathers  = (const int*)d_in[21];
    const int* sons     = (const int*)d_in[22];
    const int* grandf   = (const int*)d_in[23];
    const int* fs_nets  = (const int*)d_in[24];
    const int* gf_nets  = (const int*)d_in[25];

    char* ws = (char*)d_ws;
    size_t off = 0;
    auto alloc = [&](size_t bytes) -> void* {
        void* p = ws + off;
        off += (bytes + 255) & ~(size_t)255;
        return p;
    };
    int* cursors   = (int*)alloc(2 * 4);
    int* net_deg   = (int*)alloc((size_t)N_NET * 4);
    int* cell_deg  = (int*)alloc((size_t)N_CELL * 4);
    size_t zero_bytes = off;
    int* net_ptr   = (int*)alloc((size_t)N_NET * 4);
    int* net_cur   = (int*)alloc((size_t)N_NET * 4);
    int* cell_ptr  = (int*)alloc((size_t)N_CELL * 4);
    int* cell_cur  = (int*)alloc((size_t)N_CELL * 4);
    int* csr_net_cell = (int*)alloc((size_t)E_PIN * 4);
    int* csr_cell_net = (int*)alloc((size_t)E_PIN * 4);
    int* edge_slot    = (int*)alloc((size_t)E_PIN * 4);
    float* ew_csr   = (float*)alloc((size_t)E_PIN * 4);
    float* hnW      = (float*)alloc((size_t)N_NET * 64 * 4);
    float* npack    = (float*)alloc((size_t)N_NET * 4 * 4);
    float* cellpack = (float*)alloc((size_t)N_CELL * 8 * 4);
    if (off > ws_size) return;   // fail loudly (absmax), don't fault

    hipMemsetAsync(d_ws, 0, zero_bytes, stream);

    // CSR build
    k_hist<<<(E_PIN + 255) / 256, 256, 0, stream>>>(pins_src, pins_dst, cell_deg, net_deg);
    k_alloc<<<(N_NET + 255) / 256, 256, 0, stream>>>(net_deg, net_ptr, net_cur, &cursors[0], N_NET);
    k_alloc<<<(N_CELL + 255) / 256, 256, 0, stream>>>(cell_deg, cell_ptr, cell_cur, &cursors[1], N_CELL);
    k_fill<<<(E_PIN + 255) / 256, 256, 0, stream>>>(
        pins_src, pins_dst, net_cur, cell_cur, csr_net_cell, csr_cell_net, edge_slot);

    // edge weights into cell-CSR slot order
    k_ew<<<(E_PIN + 255) / 256, 256, 0, stream>>>(
        pin_feat, W_pin, b_pin, W_ew, b_ew, edge_slot, ew_csr);

    // fused net-side: hnW + npack
    k_net<<<(N_NET + 63) / 64, 256, 0, stream>>>(
        net_feat, cell_feat, net_ptr, net_deg, csr_net_cell,
        W_net, b_net, W_neigh, W_dis, W_def, hnW, npack);

    // fused cell-side: cellpack
    k_cell<<<N_CELL / 64, 256, 0, stream>>>(
        cell_feat, net_feat, cell_size, cell_ptr, cell_deg, csr_cell_net, ew_csr,
        hnW, W_cell, b_cell, W_self, b_sage, W_dis, W_def, cellpack);

    // edge readout
    k_edge<<<(E2 + 255) / 256, 256, 0, stream>>>(
        cellpack, npack, fathers, sons, grandf, fs_nets, gf_nets,
        b_dis, b_def, (float*)d_out);
}